// Round 16
// baseline (1249.233 us; speedup 1.0000x reference)
//
#include <hip/hip_runtime.h>

#define NB 8
#define NT 4096
#define NM 32768
#define ND 128

typedef __attribute__((ext_vector_type(8))) short bf16x8;
typedef __attribute__((ext_vector_type(4))) float f32x4;
typedef __attribute__((ext_vector_type(4))) unsigned int u32x4;
typedef __attribute__((ext_vector_type(2))) unsigned int u32x2;

#define MFMA(a,b,c) __builtin_amdgcn_mfma_f32_16x16x32_bf16(a,b,c,0,0,0)

// ---- bf16 helpers (RNE) ----
__device__ __forceinline__ unsigned short f2bf(float x) {
  unsigned u = __float_as_uint(x);
  u += 0x7FFFu + ((u >> 16) & 1u);
  return (unsigned short)(u >> 16);
}
__device__ __forceinline__ float bf2f(unsigned short h) {
  return __uint_as_float(((unsigned)h) << 16);
}
__device__ __forceinline__ u32x2 pack4bf(float a, float b, float c, float d) {
  u32x2 r;
  r[0] = ((unsigned)f2bf(b) << 16) | f2bf(a);
  r[1] = ((unsigned)f2bf(d) << 16) | f2bf(c);
  return r;
}

__device__ __forceinline__ bf16x8 ldsFrag(const char* lds, int row, int kByte, int rowStride) {
  return *(const bf16x8*)(lds + ((row * rowStride + kByte) ^ ((row & 7) << 4)));
}

// ============ weight prep (ALL weights in one launch) ============
__device__ __forceinline__ void prepOne(const float* __restrict__ W, char* __restrict__ dst,
                                        int K, int N, int khShift, int perShift, int i) {
  int m  = i >> perShift;
  int j  = i & ((1 << perShift) - 1);
  int n  = j >> khShift;
  int kh = j & ((1 << khShift) - 1);
  int k0 = kh << 3;
  const float* Wm = W + (size_t)m * K * N;
  char* dm = dst + (size_t)m * K * N * 2;
  unsigned short tmp[8];
  #pragma unroll
  for (int jj = 0; jj < 8; ++jj) tmp[jj] = f2bf(Wm[(k0 + jj) * N + n]);
  *(u32x4*)(dm + ((n * K * 2 + k0 * 2) ^ ((n & 7) << 4))) = *(u32x4*)tmp;
}

__global__ __launch_bounds__(256) void k_prep_all(
    const float* __restrict__ mlpW, const float* __restrict__ egLW,
    const float* __restrict__ nodeW,
    const float* __restrict__ nW1, const float* __restrict__ nW2,
    const float* __restrict__ eW1, const float* __restrict__ eW2,
    char* wWm, char* wWe, char* wNd, char* wN1, char* wN2, char* wE1, char* wE2)
{
  int b = blockIdx.x, t = threadIdx.x;
  if      (b < 24)  prepOne(mlpW,  wWm, 128, 128, 4, 11, b * 256 + t);
  else if (b < 48)  prepOne(egLW,  wWe, 128, 128, 4, 11, (b - 24) * 256 + t);
  else if (b < 72)  prepOne(nodeW, wNd, 128, 128, 4, 11, (b - 48) * 256 + t);
  else if (b < 88)  prepOne(nW1,   wN1, 128, 256, 4, 12, (b - 72) * 256 + t);
  else if (b < 104) prepOne(nW2,   wN2, 256, 128, 5, 12, (b - 88) * 256 + t);
  else if (b < 120) prepOne(eW1,   wE1, 128, 256, 4, 12, (b - 104) * 256 + t);
  else              prepOne(eW2,   wE2, 256, 128, 5, 12, (b - 120) * 256 + t);
}

// ================= CSR build =================
__global__ __launch_bounds__(256) void k_csr_count(const int* __restrict__ edge, int* deg) {
  int m = blockIdx.x * 256 + threadIdx.x;
  if (m < NM) atomicAdd(&deg[edge[m]], 1);
}
__global__ __launch_bounds__(64) void k_csr_scan(const int* __restrict__ deg,
                                                 int* __restrict__ off, int* __restrict__ cursor) {
  __shared__ int partial[64];
  int t = threadIdx.x;
  int base = t * 64;
  int sum = 0;
  for (int i = 0; i < 64; ++i) sum += deg[base + i];
  partial[t] = sum;
  __syncthreads();
  if (t == 0) {
    int run = 0;
    for (int i = 0; i < 64; ++i) { int v = partial[i]; partial[i] = run; run += v; }
  }
  __syncthreads();
  int run = partial[t];
  for (int i = 0; i < 64; ++i) {
    off[base + i] = run; cursor[base + i] = run;
    run += deg[base + i];
  }
  if (t == 63) off[NT] = NM;
}
__global__ __launch_bounds__(256) void k_csr_fill(const int* __restrict__ edge,
                                                  int* cursor, int* __restrict__ csr) {
  int m = blockIdx.x * 256 + threadIdx.x;
  if (m < NM) { int pos = atomicAdd(&cursor[edge[m]], 1); csr[pos] = m; }
}
__global__ __launch_bounds__(256) void k_csr_sort(const int* __restrict__ off, int* __restrict__ csr) {
  int n = blockIdx.x * 256 + threadIdx.x;
  if (n < NT) {
    int s = off[n], e = off[n + 1];
    for (int i = s + 1; i < e; ++i) {
      int v = csr[i]; int j = i - 1;
      while (j >= s && csr[j] > v) { csr[j + 1] = csr[j]; --j; }
      csr[j + 1] = v;
    }
  }
}

// ====== fused node layer (MFMA, swapped operands) ======
__global__ __launch_bounds__(256, 4) void k_node(
    const float* __restrict__ xnIn, float* __restrict__ xnOut,
    const float* __restrict__ A, const int* __restrict__ edge,
    const int* __restrict__ off, const int* __restrict__ csr,
    const char* __restrict__ WImg, const float* __restrict__ bias,
    int doReluIn, int nTiles)
{
  __shared__ __align__(16) char WT[128 * 256];
  __shared__ __align__(16) char xs[32 * 256];
  const int t = threadIdx.x;
  {
    const u32x4* s = (const u32x4*)WImg;
    u32x4* d = (u32x4*)WT;
    for (int i = t; i < 2048; i += 256) d[i] = s[i];
  }
  const int w   = t >> 6;
  const int l   = t & 63;
  const int l15 = l & 15;
  const int lg  = l >> 4;
  float4 bv4[2];
  #pragma unroll
  for (int fc = 0; fc < 2; ++fc)
    bv4[fc] = *(const float4*)(bias + w * 32 + fc * 16 + lg * 4);
  const int gr = t >> 3;
  const int c0 = (t & 7) << 4;
  __syncthreads();

  for (int tile = blockIdx.x; tile < nTiles; tile += gridDim.x) {
    const int rowBase = tile << 5;
    {
      const int grow = rowBase + gr;
      const int ch   = grow & 1;
      const int node = (grow >> 1) & (NT - 1);
      const int b    = grow >> 13;
      f32x4 acc[4];
      {
        const float4* xr = (const float4*)(xnIn + (size_t)grow * ND + c0);
        #pragma unroll
        for (int q = 0; q < 4; ++q) {
          float4 v = xr[q];
          if (doReluIn) {
            v.x = fmaxf(v.x, 0.f); v.y = fmaxf(v.y, 0.f);
            v.z = fmaxf(v.z, 0.f); v.w = fmaxf(v.w, 0.f);
          }
          acc[q] = (f32x4){v.x, v.y, v.z, v.w};
        }
      }
      const int s = off[node], e = off[node + 1];
      for (int p = s; p < e; ++p) {
        int m = csr[p];
        float a = A[b * NM + m];
        int e1 = edge[NM + m];
        const float4* src = (const float4*)(xnIn + (size_t)(((b * NT + e1) << 1) + ch) * ND + c0);
        #pragma unroll
        for (int q = 0; q < 4; ++q) {
          float4 v = src[q];
          if (doReluIn) {
            v.x = fmaxf(v.x, 0.f); v.y = fmaxf(v.y, 0.f);
            v.z = fmaxf(v.z, 0.f); v.w = fmaxf(v.w, 0.f);
          }
          acc[q][0] = fmaf(a, v.x, acc[q][0]);
          acc[q][1] = fmaf(a, v.y, acc[q][1]);
          acc[q][2] = fmaf(a, v.z, acc[q][2]);
          acc[q][3] = fmaf(a, v.w, acc[q][3]);
        }
      }
      unsigned short tmp[8];
      #pragma unroll
      for (int q = 0; q < 2; ++q)
        #pragma unroll
        for (int j = 0; j < 4; ++j) tmp[q * 4 + j] = f2bf(acc[q][j]);
      *(u32x4*)(xs + ((gr * 256 + c0 * 2) ^ ((gr & 7) << 4))) = *(u32x4*)tmp;
      #pragma unroll
      for (int q = 0; q < 2; ++q)
        #pragma unroll
        for (int j = 0; j < 4; ++j) tmp[q * 4 + j] = f2bf(acc[2 + q][j]);
      *(u32x4*)(xs + ((gr * 256 + c0 * 2 + 16) ^ ((gr & 7) << 4))) = *(u32x4*)tmp;
    }
    __syncthreads();
    f32x4 acc2[2][2];
    #pragma unroll
    for (int fr = 0; fr < 2; ++fr)
      #pragma unroll
      for (int fc = 0; fc < 2; ++fc) acc2[fr][fc] = (f32x4){0.f, 0.f, 0.f, 0.f};
    __builtin_amdgcn_s_setprio(1);
    #pragma unroll
    for (int ks = 0; ks < 4; ++ks) {
      int kb = ks * 64 + lg * 16;
      bf16x8 b0 = ldsFrag(WT, w * 32 + l15,      kb, 256);
      bf16x8 b1 = ldsFrag(WT, w * 32 + 16 + l15, kb, 256);
      bf16x8 a0 = ldsFrag(xs, l15,      kb, 256);
      bf16x8 a1 = ldsFrag(xs, 16 + l15, kb, 256);
      acc2[0][0] = MFMA(b0, a0, acc2[0][0]);
      acc2[0][1] = MFMA(b1, a0, acc2[0][1]);
      acc2[1][0] = MFMA(b0, a1, acc2[1][0]);
      acc2[1][1] = MFMA(b1, a1, acc2[1][1]);
    }
    __builtin_amdgcn_s_setprio(0);
    __syncthreads();
    #pragma unroll
    for (int fr = 0; fr < 2; ++fr)
      #pragma unroll
      for (int fc = 0; fc < 2; ++fc) {
        int row = rowBase + fr * 16 + l15;
        int col0 = w * 32 + fc * 16 + lg * 4;
        float4 o;
        o.x = acc2[fr][fc][0] + bv4[fc].x;
        o.y = acc2[fr][fc][1] + bv4[fc].y;
        o.z = acc2[fr][fc][2] + bv4[fc].z;
        o.w = acc2[fr][fc][3] + bv4[fc].w;
        *(float4*)&xnOut[(size_t)row * ND + col0] = o;
      }
  }
}

// ------ edge layer (MFMA swapped, weights in regs, 2 barriers/tile) ------
template<int IN_F32>
__global__ __launch_bounds__(512, 2) void k_edge_mfma(
    const float* __restrict__ xn,
    const float* __restrict__ xeInF, const unsigned short* __restrict__ xeInH,
    unsigned short* xeOut,
    const int* __restrict__ edge,
    const char* __restrict__ WmImg, const float* __restrict__ bm,
    const char* __restrict__ WeImg, const float* __restrict__ be,
    int doReluOut, int nTiles)
{
  __shared__ __align__(16) char sA[64 * 256];
  __shared__ __align__(16) char sB[64 * 256];
  const int t = threadIdx.x;
  const int w   = t >> 6;
  const int l   = t & 63;
  const int l15 = l & 15;
  const int lg  = l >> 4;
  const int rg2 = w >> 2;
  const int wc  = w & 3;
  bf16x8 wmf[4][2], wef[4][2];
  #pragma unroll
  for (int ks = 0; ks < 4; ++ks)
    #pragma unroll
    for (int fc = 0; fc < 2; ++fc) {
      int n = wc * 32 + fc * 16 + l15;
      int kb = ks * 64 + lg * 16;
      wmf[ks][fc] = *(const bf16x8*)(WmImg + ((n * 256 + kb) ^ ((n & 7) << 4)));
      wef[ks][fc] = *(const bf16x8*)(WeImg + ((n * 256 + kb) ^ ((n & 7) << 4)));
    }
  float4 bmv[2], bev[2];
  #pragma unroll
  for (int fc = 0; fc < 2; ++fc) {
    int col0 = wc * 32 + fc * 16 + lg * 4;
    bmv[fc] = *(const float4*)(bm + col0);
    bev[fc] = *(const float4*)(be + col0);
  }
  const int srow = t >> 3;

  for (int tile = blockIdx.x; tile < nTiles; tile += gridDim.x) {
    const int rowBase = tile << 6;
    {
      int grow = rowBase + srow;
      int cch = grow & 3;
      int m = (grow >> 2) & (NM - 1);
      int b = grow >> 17;
      int e0 = edge[m], e1 = edge[NM + m];
      const float4* p0 = (const float4*)(xn + (size_t)((b * NT + e0) * 2 + (cch >> 1)) * ND);
      const float4* p1 = (const float4*)(xn + (size_t)((b * NT + e1) * 2 + (cch & 1)) * ND);
      #pragma unroll
      for (int hh = 0; hh < 2; ++hh) {
        int h = (t & 7) + hh * 8;
        float4 a0 = p0[h * 2], a1 = p0[h * 2 + 1];
        float4 c0 = p1[h * 2], c1 = p1[h * 2 + 1];
        unsigned short tmp[8];
        tmp[0] = f2bf(a0.x + c0.x); tmp[1] = f2bf(a0.y + c0.y);
        tmp[2] = f2bf(a0.z + c0.z); tmp[3] = f2bf(a0.w + c0.w);
        tmp[4] = f2bf(a1.x + c1.x); tmp[5] = f2bf(a1.y + c1.y);
        tmp[6] = f2bf(a1.z + c1.z); tmp[7] = f2bf(a1.w + c1.w);
        *(u32x4*)(sA + ((srow * 256 + h * 16) ^ ((srow & 7) << 4))) = *(u32x4*)tmp;
      }
    }
    float4 xev[2][2];
    #pragma unroll
    for (int fr = 0; fr < 2; ++fr)
      #pragma unroll
      for (int fc = 0; fc < 2; ++fc) {
        int row = rowBase + rg2 * 32 + fr * 16 + l15;
        int col0 = wc * 32 + fc * 16 + lg * 4;
        if (IN_F32) {
          xev[fr][fc] = *(const float4*)(xeInF + (size_t)row * ND + col0);
        } else {
          ushort4 h4 = *(const ushort4*)(xeInH + (size_t)row * ND + col0);
          xev[fr][fc] = (float4){bf2f(h4.x), bf2f(h4.y), bf2f(h4.z), bf2f(h4.w)};
        }
      }
    __syncthreads();                       // B1
    f32x4 acc[2][2];
    #pragma unroll
    for (int fr = 0; fr < 2; ++fr)
      #pragma unroll
      for (int fc = 0; fc < 2; ++fc) acc[fr][fc] = (f32x4){0.f, 0.f, 0.f, 0.f};
    __builtin_amdgcn_s_setprio(1);
    #pragma unroll
    for (int ks = 0; ks < 4; ++ks) {
      int kb = ks * 64 + lg * 16;
      #pragma unroll
      for (int fr = 0; fr < 2; ++fr) {
        bf16x8 a = ldsFrag(sA, rg2 * 32 + fr * 16 + l15, kb, 256);
        acc[fr][0] = MFMA(wmf[ks][0], a, acc[fr][0]);
        acc[fr][1] = MFMA(wmf[ks][1], a, acc[fr][1]);
      }
    }
    __builtin_amdgcn_s_setprio(0);
    #pragma unroll
    for (int fr = 0; fr < 2; ++fr)
      #pragma unroll
      for (int fc = 0; fc < 2; ++fc) {
        int row = rg2 * 32 + fr * 16 + l15;
        int kByte = (wc * 32 + fc * 16 + lg * 4) * 2;
        u32x2 pk = pack4bf(xev[fr][fc].x + acc[fr][fc][0] + bmv[fc].x,
                           xev[fr][fc].y + acc[fr][fc][1] + bmv[fc].y,
                           xev[fr][fc].z + acc[fr][fc][2] + bmv[fc].z,
                           xev[fr][fc].w + acc[fr][fc][3] + bmv[fc].w);
        *(u32x2*)(sB + ((row * 256 + kByte) ^ ((row & 7) << 4))) = pk;
      }
    __syncthreads();                       // B2
    #pragma unroll
    for (int fr = 0; fr < 2; ++fr)
      #pragma unroll
      for (int fc = 0; fc < 2; ++fc) acc[fr][fc] = (f32x4){0.f, 0.f, 0.f, 0.f};
    __builtin_amdgcn_s_setprio(1);
    #pragma unroll
    for (int ks = 0; ks < 4; ++ks) {
      int kb = ks * 64 + lg * 16;
      #pragma unroll
      for (int fr = 0; fr < 2; ++fr) {
        bf16x8 a = ldsFrag(sB, rg2 * 32 + fr * 16 + l15, kb, 256);
        acc[fr][0] = MFMA(wef[ks][0], a, acc[fr][0]);
        acc[fr][1] = MFMA(wef[ks][1], a, acc[fr][1]);
      }
    }
    __builtin_amdgcn_s_setprio(0);
    #pragma unroll
    for (int fr = 0; fr < 2; ++fr)
      #pragma unroll
      for (int fc = 0; fc < 2; ++fc) {
        int row = rowBase + rg2 * 32 + fr * 16 + l15;
        int col0 = wc * 32 + fc * 16 + lg * 4;
        float o0 = acc[fr][fc][0] + bev[fc].x;
        float o1 = acc[fr][fc][1] + bev[fc].y;
        float o2 = acc[fr][fc][2] + bev[fc].z;
        float o3 = acc[fr][fc][3] + bev[fc].w;
        if (doReluOut) {
          o0 = fmaxf(o0, 0.f); o1 = fmaxf(o1, 0.f);
          o2 = fmaxf(o2, 0.f); o3 = fmaxf(o3, 0.f);
        }
        u32x2 pk = pack4bf(o0, o1, o2, o3);
        *(u32x2*)(xeOut + (size_t)row * ND + col0) = pk;
      }
  }
}

// ====== fused readout (swapped): 64-row tiles, 2 barriers/tile, weights in regs ======
template<int INBF16>
__global__ __launch_bounds__(512, 2) void k_ro_fused(
    const float* __restrict__ inF, const unsigned short* __restrict__ inH,
    float* __restrict__ out, int nTiles,
    const char* __restrict__ W1Img, const float* __restrict__ b1,
    const char* __restrict__ W2Img, const float* __restrict__ b2,
    const float* __restrict__ W3, const float* __restrict__ b3)
{
  __shared__ __align__(16) char sA[64 * 256];
  __shared__ __align__(16) char h1[64 * 512];
  __shared__ float red[2][64][8];
  const int t = threadIdx.x;
  const int w   = t >> 6;
  const int l   = t & 63;
  const int l15 = l & 15;
  const int lg  = l >> 4;
  bf16x8 w1f[4][2];
  #pragma unroll
  for (int ks = 0; ks < 4; ++ks)
    #pragma unroll
    for (int fc = 0; fc < 2; ++fc) {
      int n = w * 32 + fc * 16 + l15;
      int kb = ks * 64 + lg * 16;
      w1f[ks][fc] = *(const bf16x8*)(W1Img + ((n * 256 + kb) ^ ((n & 7) << 4)));
    }
  bf16x8 w2f[8];
  #pragma unroll
  for (int ks = 0; ks < 8; ++ks) {
    int n = w * 16 + l15;
    int kb = ks * 64 + lg * 16;
    w2f[ks] = *(const bf16x8*)(W2Img + ((n * 512 + kb) ^ ((n & 7) << 4)));
  }
  float4 b1v[2];
  #pragma unroll
  for (int fc = 0; fc < 2; ++fc)
    b1v[fc] = *(const float4*)(b1 + w * 32 + fc * 16 + lg * 4);
  const float4 b2v = *(const float4*)(b2 + w * 16 + lg * 4);
  const float4 w3v = *(const float4*)(W3 + w * 16 + lg * 4);
  const float b3v = b3[0];
  const int srow  = t >> 3;
  const int sbyte = (t & 7) << 5;
  u32x4 pvH[2];
  int tile = blockIdx.x;
  if (tile < nTiles) {
    if (INBF16) {
      const char* p = (const char*)inH + (size_t)((tile << 6) + srow) * 256 + sbyte;
      pvH[0] = *(const u32x4*)p;
      pvH[1] = *(const u32x4*)(p + 16);
    } else {
      const float4* p = (const float4*)(inF + (size_t)((tile << 6) + srow) * ND + ((t & 7) << 4));
      unsigned short tmp[16];
      #pragma unroll
      for (int q = 0; q < 4; ++q) {
        float4 v = p[q];
        tmp[q * 4 + 0] = f2bf(v.x); tmp[q * 4 + 1] = f2bf(v.y);
        tmp[q * 4 + 2] = f2bf(v.z); tmp[q * 4 + 3] = f2bf(v.w);
      }
      pvH[0] = *(u32x4*)tmp; pvH[1] = *(u32x4*)(tmp + 8);
    }
  }

  int par = 0;
  int prevRow = -1;
  for (; tile < nTiles; tile += gridDim.x) {
    const int rowBase = tile << 6;
    *(u32x4*)(sA + ((srow * 256 + sbyte) ^ ((srow & 7) << 4))) = pvH[0];
    *(u32x4*)(sA + ((srow * 256 + sbyte + 16) ^ ((srow & 7) << 4))) = pvH[1];
    __syncthreads();                                   // B1
    if (prevRow >= 0 && t < 64) {
      float s = b3v;
      #pragma unroll
      for (int q = 0; q < 8; ++q) s += red[par ^ 1][t][q];
      out[prevRow + t] = s;
    }
    {
      int nt2 = tile + (int)gridDim.x;
      if (nt2 < nTiles) {
        if (INBF16) {
          const char* p = (const char*)inH + (size_t)((nt2 << 6) + srow) * 256 + sbyte;
          pvH[0] = *(const u32x4*)p;
          pvH[1] = *(const u32x4*)(p + 16);
        } else {
          const float4* p = (const float4*)(inF + (size_t)((nt2 << 6) + srow) * ND + ((t & 7) << 4));
          unsigned short tmp[16];
          #pragma unroll
          for (int q = 0; q < 4; ++q) {
            float4 v = p[q];
            tmp[q * 4 + 0] = f2bf(v.x); tmp[q * 4 + 1] = f2bf(v.y);
            tmp[q * 4 + 2] = f2bf(v.z); tmp[q * 4 + 3] = f2bf(v.w);
          }
          pvH[0] = *(u32x4*)tmp; pvH[1] = *(u32x4*)(tmp + 8);
        }
      }
    }
    {
      f32x4 acc[4][2];
      #pragma unroll
      for (int fr = 0; fr < 4; ++fr)
        #pragma unroll
        for (int fc = 0; fc < 2; ++fc) acc[fr][fc] = (f32x4){0.f, 0.f, 0.f, 0.f};
      __builtin_amdgcn_s_setprio(1);
      #pragma unroll
      for (int ks = 0; ks < 4; ++ks) {
        int kb = ks * 64 + lg * 16;
        #pragma unroll
        for (int fr = 0; fr < 4; ++fr) {
          bf16x8 a = ldsFrag(sA, fr * 16 + l15, kb, 256);
          acc[fr][0] = MFMA(w1f[ks][0], a, acc[fr][0]);
          acc[fr][1] = MFMA(w1f[ks][1], a, acc[fr][1]);
        }
      }
      __builtin_amdgcn_s_setprio(0);
      #pragma unroll
      for (int fr = 0; fr < 4; ++fr)
        #pragma unroll
        for (int fc = 0; fc < 2; ++fc) {
          int row = fr * 16 + l15;
          int kByte = (w * 32 + fc * 16 + lg * 4) * 2;
          u32x2 pk = pack4bf(fmaxf(acc[fr][fc][0] + b1v[fc].x, 0.f),
                             fmaxf(acc[fr][fc][1] + b1v[fc].y, 0.f),
                             fmaxf(acc[fr][fc][2] + b1v[fc].z, 0.f),
                             fmaxf(acc[fr][fc][3] + b1v[fc].w, 0.f));
          *(u32x2*)(h1 + ((row * 512 + kByte) ^ ((row & 7) << 4))) = pk;
        }
    }
    __syncthreads();                                   // B2
    {
      f32x4 acc[4];
      #pragma unroll
      for (int fr = 0; fr < 4; ++fr) acc[fr] = (f32x4){0.f, 0.f, 0.f, 0.f};
      __builtin_amdgcn_s_setprio(1);
      #pragma unroll
      for (int ks = 0; ks < 8; ++ks) {
        int kb = ks * 64 + lg * 16;
        #pragma unroll
        for (int fr = 0; fr < 4; ++fr) {
          bf16x8 a = ldsFrag(h1, fr * 16 + l15, kb, 512);
          acc[fr] = MFMA(w2f[ks], a, acc[fr]);
        }
      }
      __builtin_amdgcn_s_setprio(0);
      #pragma unroll
      for (int fr = 0; fr < 4; ++fr) {
        float p = fmaxf(acc[fr][0] + b2v.x, 0.f) * w3v.x
                + fmaxf(acc[fr][1] + b2v.y, 0.f) * w3v.y
                + fmaxf(acc[fr][2] + b2v.z, 0.f) * w3v.z
                + fmaxf(acc[fr][3] + b2v.w, 0.f) * w3v.w;
        p += __shfl_xor(p, 16);
        p += __shfl_xor(p, 32);
        if (lg == 0) red[par][fr * 16 + l15][w] = p;
      }
    }
    prevRow = rowBase;
    par ^= 1;
  }
  __syncthreads();
  if (prevRow >= 0 && t < 64) {
    float s = b3v;
    #pragma unroll
    for (int q = 0; q < 8; ++q) s += red[par ^ 1][t][q];
    out[prevRow + t] = s;
  }
}

extern "C" void kernel_launch(void* const* d_in, const int* in_sizes, int n_in,
                              void* d_out, int out_size, void* d_ws, size_t ws_size,
                              hipStream_t stream)
{
  const float* x1     = (const float*)d_in[0];
  const float* x2     = (const float*)d_in[1];
  const float* Ac     = (const float*)d_in[2];
  const int*   edge   = (const int*)d_in[3];
  const float* node_W = (const float*)d_in[4];
  const float* node_b = (const float*)d_in[5];
  const float* mlp_W  = (const float*)d_in[6];
  const float* mlp_b  = (const float*)d_in[7];
  const float* egL_W  = (const float*)d_in[8];
  const float* egL_b  = (const float*)d_in[9];
  const float* nro_W1 = (const float*)d_in[10];
  const float* nro_b1 = (const float*)d_in[11];
  const float* nro_W2 = (const float*)d_in[12];
  const float* nro_b2 = (const float*)d_in[13];
  const float* nro_W3 = (const float*)d_in[14];
  const float* nro_b3 = (const float*)d_in[15];
  const float* ero_W1 = (const float*)d_in[16];
  const float* ero_b1 = (const float*)d_in[17];
  const float* ero_W2 = (const float*)d_in[18];
  const float* ero_b2 = (const float*)d_in[19];
  const float* ero_W3 = (const float*)d_in[20];
  const float* ero_b3 = (const float*)d_in[21];
  float* out = (float*)d_out;

  const size_t xnElems = (size_t)NB * NT * 2 * ND;       // 8,388,608
  const size_t xeElems = (size_t)NB * NM * 4 * ND;       // 134,217,728
  const size_t wBytes  = 3 * 128 * 128 * 2 * 3
                       + 4 * (128 * 256 * 2);
  if (ws_size < xnElems * 3 * sizeof(float) + xeElems * 2 + wBytes) return;

  float* xn0 = (float*)d_ws;
  float* xn1 = xn0 + xnElems;
  float* xn2 = xn1 + xnElems;
  unsigned short* xeH = (unsigned short*)(xn2 + xnElems);
  char*  wWm = (char*)(xeH + xeElems);
  char*  wWe = wWm + 3 * 128 * 128 * 2;
  char*  wNd = wWe + 3 * 128 * 128 * 2;
  char*  wN1 = wNd + 3 * 128 * 128 * 2;
  char*  wN2 = wN1 + 128 * 256 * 2;
  char*  wE1 = wN2 + 128 * 256 * 2;
  char*  wE2 = wE1 + 128 * 256 * 2;

  int* deg    = (int*)d_out;
  int* off    = deg + NT;
  int* cursor = off + NT + 1;
  int* csr    = cursor + NT;

  // all weight prep in one launch (136 blocks)
  k_prep_all<<<136, 256, 0, stream>>>(mlp_W, egL_W, node_W,
                                      nro_W1, nro_W2, ero_W1, ero_W2,
                                      wWm, wWe, wNd, wN1, wN2, wE1, wE2);

  hipMemsetAsync(deg, 0, NT * sizeof(int), stream);
  k_csr_count<<<NM / 256, 256, 0, stream>>>(edge, deg);
  k_csr_scan<<<1, 64, 0, stream>>>(deg, off, cursor);
  k_csr_fill<<<NM / 256, 256, 0, stream>>>(edge, cursor, csr);
  k_csr_sort<<<NT / 256, 256, 0, stream>>>(off, csr);

  const int nTilesN = (NB * NT * 2) / 32;  // 2048
  k_node<<<1024, 256, 0, stream>>>(x1, xn0, Ac, edge, off, csr, wNd, node_b, 0, nTilesN);
  k_node<<<1024, 256, 0, stream>>>(xn0, xn1, Ac, edge, off, csr,
                                   wNd + 128 * 128 * 2, node_b + ND, 1, nTilesN);
  k_node<<<1024, 256, 0, stream>>>(xn1, xn2, Ac, edge, off, csr,
                                   wNd + 2 * 128 * 128 * 2, node_b + 2 * ND, 1, nTilesN);

  const int eTiles = (NB * NM * 4) / 64;   // 16384
  k_edge_mfma<1><<<512, 512, 0, stream>>>(xn0, x2, nullptr, xeH, edge,
                                          wWm, mlp_b, wWe, egL_b, 1, eTiles);
  k_edge_mfma<0><<<512, 512, 0, stream>>>(xn1, nullptr, xeH, xeH, edge,
                                          wWm + 128 * 128 * 2, mlp_b + ND,
                                          wWe + 128 * 128 * 2, egL_b + ND, 1, eTiles);
  k_edge_mfma<0><<<512, 512, 0, stream>>>(xn2, nullptr, xeH, xeH, edge,
                                          wWm + 2 * 128 * 128 * 2, mlp_b + 2 * ND,
                                          wWe + 2 * 128 * 128 * 2, egL_b + 2 * ND, 0, eTiles);
  k_ro_fused<1><<<512, 512, 0, stream>>>(nullptr, xeH, out + NB * NT * 2, eTiles,
                                         wE1, ero_b1, wE2, ero_b2, ero_W3, ero_b3);
  k_ro_fused<0><<<512, 512, 0, stream>>>(xn2, nullptr, out, (NB * NT * 2) / 64,
                                         wN1, nro_b1, wN2, nro_b2, nro_W3, nro_b3);
}

// Round 17
// 1210.304 us; speedup vs baseline: 1.0322x; 1.0322x over previous
//
#include <hip/hip_runtime.h>

#define NB 8
#define NT 4096
#define NM 32768
#define ND 128

typedef __attribute__((ext_vector_type(8))) short bf16x8;
typedef __attribute__((ext_vector_type(4))) float f32x4;
typedef __attribute__((ext_vector_type(4))) unsigned int u32x4;
typedef __attribute__((ext_vector_type(2))) unsigned int u32x2;

#define MFMA(a,b,c) __builtin_amdgcn_mfma_f32_16x16x32_bf16(a,b,c,0,0,0)

// ---- bf16 helpers (RNE) ----
__device__ __forceinline__ unsigned short f2bf(float x) {
  unsigned u = __float_as_uint(x);
  u += 0x7FFFu + ((u >> 16) & 1u);
  return (unsigned short)(u >> 16);
}
__device__ __forceinline__ float bf2f(unsigned short h) {
  return __uint_as_float(((unsigned)h) << 16);
}
__device__ __forceinline__ u32x2 pack4bf(float a, float b, float c, float d) {
  u32x2 r;
  r[0] = ((unsigned)f2bf(b) << 16) | f2bf(a);
  r[1] = ((unsigned)f2bf(d) << 16) | f2bf(c);
  return r;
}

__device__ __forceinline__ bf16x8 ldsFrag(const char* lds, int row, int kByte, int rowStride) {
  return *(const bf16x8*)(lds + ((row * rowStride + kByte) ^ ((row & 7) << 4)));
}

// ============ weight prep (ALL weights in one launch) ============
__device__ __forceinline__ void prepOne(const float* __restrict__ W, char* __restrict__ dst,
                                        int K, int N, int khShift, int perShift, int i) {
  int m  = i >> perShift;
  int j  = i & ((1 << perShift) - 1);
  int n  = j >> khShift;
  int kh = j & ((1 << khShift) - 1);
  int k0 = kh << 3;
  const float* Wm = W + (size_t)m * K * N;
  char* dm = dst + (size_t)m * K * N * 2;
  unsigned short tmp[8];
  #pragma unroll
  for (int jj = 0; jj < 8; ++jj) tmp[jj] = f2bf(Wm[(k0 + jj) * N + n]);
  *(u32x4*)(dm + ((n * K * 2 + k0 * 2) ^ ((n & 7) << 4))) = *(u32x4*)tmp;
}

__global__ __launch_bounds__(256) void k_prep_all(
    const float* __restrict__ mlpW, const float* __restrict__ egLW,
    const float* __restrict__ nodeW,
    const float* __restrict__ nW1, const float* __restrict__ nW2,
    const float* __restrict__ eW1, const float* __restrict__ eW2,
    char* wWm, char* wWe, char* wNd, char* wN1, char* wN2, char* wE1, char* wE2)
{
  int b = blockIdx.x, t = threadIdx.x;
  if      (b < 24)  prepOne(mlpW,  wWm, 128, 128, 4, 11, b * 256 + t);
  else if (b < 48)  prepOne(egLW,  wWe, 128, 128, 4, 11, (b - 24) * 256 + t);
  else if (b < 72)  prepOne(nodeW, wNd, 128, 128, 4, 11, (b - 48) * 256 + t);
  else if (b < 88)  prepOne(nW1,   wN1, 128, 256, 4, 12, (b - 72) * 256 + t);
  else if (b < 104) prepOne(nW2,   wN2, 256, 128, 5, 12, (b - 88) * 256 + t);
  else if (b < 120) prepOne(eW1,   wE1, 128, 256, 4, 12, (b - 104) * 256 + t);
  else              prepOne(eW2,   wE2, 256, 128, 5, 12, (b - 120) * 256 + t);
}

// ================= CSR build =================
__global__ __launch_bounds__(256) void k_csr_count(const int* __restrict__ edge, int* deg) {
  int m = blockIdx.x * 256 + threadIdx.x;
  if (m < NM) atomicAdd(&deg[edge[m]], 1);
}
__global__ __launch_bounds__(64) void k_csr_scan(const int* __restrict__ deg,
                                                 int* __restrict__ off, int* __restrict__ cursor) {
  __shared__ int partial[64];
  int t = threadIdx.x;
  int base = t * 64;
  int sum = 0;
  for (int i = 0; i < 64; ++i) sum += deg[base + i];
  partial[t] = sum;
  __syncthreads();
  if (t == 0) {
    int run = 0;
    for (int i = 0; i < 64; ++i) { int v = partial[i]; partial[i] = run; run += v; }
  }
  __syncthreads();
  int run = partial[t];
  for (int i = 0; i < 64; ++i) {
    off[base + i] = run; cursor[base + i] = run;
    run += deg[base + i];
  }
  if (t == 63) off[NT] = NM;
}
__global__ __launch_bounds__(256) void k_csr_fill(const int* __restrict__ edge,
                                                  int* cursor, int* __restrict__ csr) {
  int m = blockIdx.x * 256 + threadIdx.x;
  if (m < NM) { int pos = atomicAdd(&cursor[edge[m]], 1); csr[pos] = m; }
}
__global__ __launch_bounds__(256) void k_csr_sort(const int* __restrict__ off, int* __restrict__ csr) {
  int n = blockIdx.x * 256 + threadIdx.x;
  if (n < NT) {
    int s = off[n], e = off[n + 1];
    for (int i = s + 1; i < e; ++i) {
      int v = csr[i]; int j = i - 1;
      while (j >= s && csr[j] > v) { csr[j + 1] = csr[j]; --j; }
      csr[j + 1] = v;
    }
  }
}

// ====== fused node layer (MFMA, swapped operands) ======
__global__ __launch_bounds__(256, 4) void k_node(
    const float* __restrict__ xnIn, float* __restrict__ xnOut,
    const float* __restrict__ A, const int* __restrict__ edge,
    const int* __restrict__ off, const int* __restrict__ csr,
    const char* __restrict__ WImg, const float* __restrict__ bias,
    int doReluIn, int nTiles)
{
  __shared__ __align__(16) char WT[128 * 256];
  __shared__ __align__(16) char xs[32 * 256];
  const int t = threadIdx.x;
  {
    const u32x4* s = (const u32x4*)WImg;
    u32x4* d = (u32x4*)WT;
    for (int i = t; i < 2048; i += 256) d[i] = s[i];
  }
  const int w   = t >> 6;
  const int l   = t & 63;
  const int l15 = l & 15;
  const int lg  = l >> 4;
  float4 bv4[2];
  #pragma unroll
  for (int fc = 0; fc < 2; ++fc)
    bv4[fc] = *(const float4*)(bias + w * 32 + fc * 16 + lg * 4);
  const int gr = t >> 3;
  const int c0 = (t & 7) << 4;
  __syncthreads();

  for (int tile = blockIdx.x; tile < nTiles; tile += gridDim.x) {
    const int rowBase = tile << 5;
    {
      const int grow = rowBase + gr;
      const int ch   = grow & 1;
      const int node = (grow >> 1) & (NT - 1);
      const int b    = grow >> 13;
      f32x4 acc[4];
      {
        const float4* xr = (const float4*)(xnIn + (size_t)grow * ND + c0);
        #pragma unroll
        for (int q = 0; q < 4; ++q) {
          float4 v = xr[q];
          if (doReluIn) {
            v.x = fmaxf(v.x, 0.f); v.y = fmaxf(v.y, 0.f);
            v.z = fmaxf(v.z, 0.f); v.w = fmaxf(v.w, 0.f);
          }
          acc[q] = (f32x4){v.x, v.y, v.z, v.w};
        }
      }
      const int s = off[node], e = off[node + 1];
      for (int p = s; p < e; ++p) {
        int m = csr[p];
        float a = A[b * NM + m];
        int e1 = edge[NM + m];
        const float4* src = (const float4*)(xnIn + (size_t)(((b * NT + e1) << 1) + ch) * ND + c0);
        #pragma unroll
        for (int q = 0; q < 4; ++q) {
          float4 v = src[q];
          if (doReluIn) {
            v.x = fmaxf(v.x, 0.f); v.y = fmaxf(v.y, 0.f);
            v.z = fmaxf(v.z, 0.f); v.w = fmaxf(v.w, 0.f);
          }
          acc[q][0] = fmaf(a, v.x, acc[q][0]);
          acc[q][1] = fmaf(a, v.y, acc[q][1]);
          acc[q][2] = fmaf(a, v.z, acc[q][2]);
          acc[q][3] = fmaf(a, v.w, acc[q][3]);
        }
      }
      unsigned short tmp[8];
      #pragma unroll
      for (int q = 0; q < 2; ++q)
        #pragma unroll
        for (int j = 0; j < 4; ++j) tmp[q * 4 + j] = f2bf(acc[q][j]);
      *(u32x4*)(xs + ((gr * 256 + c0 * 2) ^ ((gr & 7) << 4))) = *(u32x4*)tmp;
      #pragma unroll
      for (int q = 0; q < 2; ++q)
        #pragma unroll
        for (int j = 0; j < 4; ++j) tmp[q * 4 + j] = f2bf(acc[2 + q][j]);
      *(u32x4*)(xs + ((gr * 256 + c0 * 2 + 16) ^ ((gr & 7) << 4))) = *(u32x4*)tmp;
    }
    __syncthreads();
    f32x4 acc2[2][2];
    #pragma unroll
    for (int fr = 0; fr < 2; ++fr)
      #pragma unroll
      for (int fc = 0; fc < 2; ++fc) acc2[fr][fc] = (f32x4){0.f, 0.f, 0.f, 0.f};
    #pragma unroll
    for (int ks = 0; ks < 4; ++ks) {
      int kb = ks * 64 + lg * 16;
      bf16x8 b0 = ldsFrag(WT, w * 32 + l15,      kb, 256);
      bf16x8 b1 = ldsFrag(WT, w * 32 + 16 + l15, kb, 256);
      bf16x8 a0 = ldsFrag(xs, l15,      kb, 256);
      bf16x8 a1 = ldsFrag(xs, 16 + l15, kb, 256);
      acc2[0][0] = MFMA(b0, a0, acc2[0][0]);
      acc2[0][1] = MFMA(b1, a0, acc2[0][1]);
      acc2[1][0] = MFMA(b0, a1, acc2[1][0]);
      acc2[1][1] = MFMA(b1, a1, acc2[1][1]);
    }
    __syncthreads();
    #pragma unroll
    for (int fr = 0; fr < 2; ++fr)
      #pragma unroll
      for (int fc = 0; fc < 2; ++fc) {
        int row = rowBase + fr * 16 + l15;
        int col0 = w * 32 + fc * 16 + lg * 4;
        float4 o;
        o.x = acc2[fr][fc][0] + bv4[fc].x;
        o.y = acc2[fr][fc][1] + bv4[fc].y;
        o.z = acc2[fr][fc][2] + bv4[fc].z;
        o.w = acc2[fr][fc][3] + bv4[fc].w;
        *(float4*)&xnOut[(size_t)row * ND + col0] = o;
      }
  }
}

// ------ edge layer (MFMA swapped, weights in regs, 2 barriers/tile) ------
template<int IN_F32>
__global__ __launch_bounds__(512, 2) void k_edge_mfma(
    const float* __restrict__ xn,
    const float* __restrict__ xeInF, const unsigned short* __restrict__ xeInH,
    unsigned short* xeOut,
    const int* __restrict__ edge,
    const char* __restrict__ WmImg, const float* __restrict__ bm,
    const char* __restrict__ WeImg, const float* __restrict__ be,
    int doReluOut, int nTiles)
{
  __shared__ __align__(16) char sA[64 * 256];
  __shared__ __align__(16) char sB[64 * 256];
  const int t = threadIdx.x;
  const int w   = t >> 6;
  const int l   = t & 63;
  const int l15 = l & 15;
  const int lg  = l >> 4;
  const int rg2 = w >> 2;
  const int wc  = w & 3;
  bf16x8 wmf[4][2], wef[4][2];
  #pragma unroll
  for (int ks = 0; ks < 4; ++ks)
    #pragma unroll
    for (int fc = 0; fc < 2; ++fc) {
      int n = wc * 32 + fc * 16 + l15;
      int kb = ks * 64 + lg * 16;
      wmf[ks][fc] = *(const bf16x8*)(WmImg + ((n * 256 + kb) ^ ((n & 7) << 4)));
      wef[ks][fc] = *(const bf16x8*)(WeImg + ((n * 256 + kb) ^ ((n & 7) << 4)));
    }
  float4 bmv[2], bev[2];
  #pragma unroll
  for (int fc = 0; fc < 2; ++fc) {
    int col0 = wc * 32 + fc * 16 + lg * 4;
    bmv[fc] = *(const float4*)(bm + col0);
    bev[fc] = *(const float4*)(be + col0);
  }
  const int srow = t >> 3;

  for (int tile = blockIdx.x; tile < nTiles; tile += gridDim.x) {
    const int rowBase = tile << 6;
    {
      int grow = rowBase + srow;
      int cch = grow & 3;
      int m = (grow >> 2) & (NM - 1);
      int b = grow >> 17;
      int e0 = edge[m], e1 = edge[NM + m];
      const float4* p0 = (const float4*)(xn + (size_t)((b * NT + e0) * 2 + (cch >> 1)) * ND);
      const float4* p1 = (const float4*)(xn + (size_t)((b * NT + e1) * 2 + (cch & 1)) * ND);
      #pragma unroll
      for (int hh = 0; hh < 2; ++hh) {
        int h = (t & 7) + hh * 8;
        float4 a0 = p0[h * 2], a1 = p0[h * 2 + 1];
        float4 c0 = p1[h * 2], c1 = p1[h * 2 + 1];
        unsigned short tmp[8];
        tmp[0] = f2bf(a0.x + c0.x); tmp[1] = f2bf(a0.y + c0.y);
        tmp[2] = f2bf(a0.z + c0.z); tmp[3] = f2bf(a0.w + c0.w);
        tmp[4] = f2bf(a1.x + c1.x); tmp[5] = f2bf(a1.y + c1.y);
        tmp[6] = f2bf(a1.z + c1.z); tmp[7] = f2bf(a1.w + c1.w);
        *(u32x4*)(sA + ((srow * 256 + h * 16) ^ ((srow & 7) << 4))) = *(u32x4*)tmp;
      }
    }
    float4 xev[2][2];
    #pragma unroll
    for (int fr = 0; fr < 2; ++fr)
      #pragma unroll
      for (int fc = 0; fc < 2; ++fc) {
        int row = rowBase + rg2 * 32 + fr * 16 + l15;
        int col0 = wc * 32 + fc * 16 + lg * 4;
        if (IN_F32) {
          xev[fr][fc] = *(const float4*)(xeInF + (size_t)row * ND + col0);
        } else {
          ushort4 h4 = *(const ushort4*)(xeInH + (size_t)row * ND + col0);
          xev[fr][fc] = (float4){bf2f(h4.x), bf2f(h4.y), bf2f(h4.z), bf2f(h4.w)};
        }
      }
    __syncthreads();                       // B1
    f32x4 acc[2][2];
    #pragma unroll
    for (int fr = 0; fr < 2; ++fr)
      #pragma unroll
      for (int fc = 0; fc < 2; ++fc) acc[fr][fc] = (f32x4){0.f, 0.f, 0.f, 0.f};
    #pragma unroll
    for (int ks = 0; ks < 4; ++ks) {
      int kb = ks * 64 + lg * 16;
      #pragma unroll
      for (int fr = 0; fr < 2; ++fr) {
        bf16x8 a = ldsFrag(sA, rg2 * 32 + fr * 16 + l15, kb, 256);
        acc[fr][0] = MFMA(wmf[ks][0], a, acc[fr][0]);
        acc[fr][1] = MFMA(wmf[ks][1], a, acc[fr][1]);
      }
    }
    #pragma unroll
    for (int fr = 0; fr < 2; ++fr)
      #pragma unroll
      for (int fc = 0; fc < 2; ++fc) {
        int row = rg2 * 32 + fr * 16 + l15;
        int kByte = (wc * 32 + fc * 16 + lg * 4) * 2;
        u32x2 pk = pack4bf(xev[fr][fc].x + acc[fr][fc][0] + bmv[fc].x,
                           xev[fr][fc].y + acc[fr][fc][1] + bmv[fc].y,
                           xev[fr][fc].z + acc[fr][fc][2] + bmv[fc].z,
                           xev[fr][fc].w + acc[fr][fc][3] + bmv[fc].w);
        *(u32x2*)(sB + ((row * 256 + kByte) ^ ((row & 7) << 4))) = pk;
      }
    __syncthreads();                       // B2
    #pragma unroll
    for (int fr = 0; fr < 2; ++fr)
      #pragma unroll
      for (int fc = 0; fc < 2; ++fc) acc[fr][fc] = (f32x4){0.f, 0.f, 0.f, 0.f};
    #pragma unroll
    for (int ks = 0; ks < 4; ++ks) {
      int kb = ks * 64 + lg * 16;
      #pragma unroll
      for (int fr = 0; fr < 2; ++fr) {
        bf16x8 a = ldsFrag(sB, rg2 * 32 + fr * 16 + l15, kb, 256);
        acc[fr][0] = MFMA(wef[ks][0], a, acc[fr][0]);
        acc[fr][1] = MFMA(wef[ks][1], a, acc[fr][1]);
      }
    }
    #pragma unroll
    for (int fr = 0; fr < 2; ++fr)
      #pragma unroll
      for (int fc = 0; fc < 2; ++fc) {
        int row = rowBase + rg2 * 32 + fr * 16 + l15;
        int col0 = wc * 32 + fc * 16 + lg * 4;
        float o0 = acc[fr][fc][0] + bev[fc].x;
        float o1 = acc[fr][fc][1] + bev[fc].y;
        float o2 = acc[fr][fc][2] + bev[fc].z;
        float o3 = acc[fr][fc][3] + bev[fc].w;
        if (doReluOut) {
          o0 = fmaxf(o0, 0.f); o1 = fmaxf(o1, 0.f);
          o2 = fmaxf(o2, 0.f); o3 = fmaxf(o3, 0.f);
        }
        u32x2 pk = pack4bf(o0, o1, o2, o3);
        *(u32x2*)(xeOut + (size_t)row * ND + col0) = pk;
      }
  }
}

// ====== fused readout (swapped): 64-row tiles, 2 barriers/tile, weights in regs ======
template<int INBF16>
__global__ __launch_bounds__(512, 2) void k_ro_fused(
    const float* __restrict__ inF, const unsigned short* __restrict__ inH,
    float* __restrict__ out, int nTiles,
    const char* __restrict__ W1Img, const float* __restrict__ b1,
    const char* __restrict__ W2Img, const float* __restrict__ b2,
    const float* __restrict__ W3, const float* __restrict__ b3)
{
  __shared__ __align__(16) char sA[64 * 256];
  __shared__ __align__(16) char h1[64 * 512];
  __shared__ float red[2][64][8];
  const int t = threadIdx.x;
  const int w   = t >> 6;
  const int l   = t & 63;
  const int l15 = l & 15;
  const int lg  = l >> 4;
  bf16x8 w1f[4][2];
  #pragma unroll
  for (int ks = 0; ks < 4; ++ks)
    #pragma unroll
    for (int fc = 0; fc < 2; ++fc) {
      int n = w * 32 + fc * 16 + l15;
      int kb = ks * 64 + lg * 16;
      w1f[ks][fc] = *(const bf16x8*)(W1Img + ((n * 256 + kb) ^ ((n & 7) << 4)));
    }
  bf16x8 w2f[8];
  #pragma unroll
  for (int ks = 0; ks < 8; ++ks) {
    int n = w * 16 + l15;
    int kb = ks * 64 + lg * 16;
    w2f[ks] = *(const bf16x8*)(W2Img + ((n * 512 + kb) ^ ((n & 7) << 4)));
  }
  float4 b1v[2];
  #pragma unroll
  for (int fc = 0; fc < 2; ++fc)
    b1v[fc] = *(const float4*)(b1 + w * 32 + fc * 16 + lg * 4);
  const float4 b2v = *(const float4*)(b2 + w * 16 + lg * 4);
  const float4 w3v = *(const float4*)(W3 + w * 16 + lg * 4);
  const float b3v = b3[0];
  const int srow  = t >> 3;
  const int sbyte = (t & 7) << 5;
  u32x4 pvH[2];
  int tile = blockIdx.x;
  if (tile < nTiles) {
    if (INBF16) {
      const char* p = (const char*)inH + (size_t)((tile << 6) + srow) * 256 + sbyte;
      pvH[0] = *(const u32x4*)p;
      pvH[1] = *(const u32x4*)(p + 16);
    } else {
      const float4* p = (const float4*)(inF + (size_t)((tile << 6) + srow) * ND + ((t & 7) << 4));
      unsigned short tmp[16];
      #pragma unroll
      for (int q = 0; q < 4; ++q) {
        float4 v = p[q];
        tmp[q * 4 + 0] = f2bf(v.x); tmp[q * 4 + 1] = f2bf(v.y);
        tmp[q * 4 + 2] = f2bf(v.z); tmp[q * 4 + 3] = f2bf(v.w);
      }
      pvH[0] = *(u32x4*)tmp; pvH[1] = *(u32x4*)(tmp + 8);
    }
  }

  int par = 0;
  int prevRow = -1;
  for (; tile < nTiles; tile += gridDim.x) {
    const int rowBase = tile << 6;
    *(u32x4*)(sA + ((srow * 256 + sbyte) ^ ((srow & 7) << 4))) = pvH[0];
    *(u32x4*)(sA + ((srow * 256 + sbyte + 16) ^ ((srow & 7) << 4))) = pvH[1];
    __syncthreads();                                   // B1
    if (prevRow >= 0 && t < 64) {
      float s = b3v;
      #pragma unroll
      for (int q = 0; q < 8; ++q) s += red[par ^ 1][t][q];
      out[prevRow + t] = s;
    }
    {
      int nt2 = tile + (int)gridDim.x;
      if (nt2 < nTiles) {
        if (INBF16) {
          const char* p = (const char*)inH + (size_t)((nt2 << 6) + srow) * 256 + sbyte;
          pvH[0] = *(const u32x4*)p;
          pvH[1] = *(const u32x4*)(p + 16);
        } else {
          const float4* p = (const float4*)(inF + (size_t)((nt2 << 6) + srow) * ND + ((t & 7) << 4));
          unsigned short tmp[16];
          #pragma unroll
          for (int q = 0; q < 4; ++q) {
            float4 v = p[q];
            tmp[q * 4 + 0] = f2bf(v.x); tmp[q * 4 + 1] = f2bf(v.y);
            tmp[q * 4 + 2] = f2bf(v.z); tmp[q * 4 + 3] = f2bf(v.w);
          }
          pvH[0] = *(u32x4*)tmp; pvH[1] = *(u32x4*)(tmp + 8);
        }
      }
    }
    {
      f32x4 acc[4][2];
      #pragma unroll
      for (int fr = 0; fr < 4; ++fr)
        #pragma unroll
        for (int fc = 0; fc < 2; ++fc) acc[fr][fc] = (f32x4){0.f, 0.f, 0.f, 0.f};
      #pragma unroll
      for (int ks = 0; ks < 4; ++ks) {
        int kb = ks * 64 + lg * 16;
        #pragma unroll
        for (int fr = 0; fr < 4; ++fr) {
          bf16x8 a = ldsFrag(sA, fr * 16 + l15, kb, 256);
          acc[fr][0] = MFMA(w1f[ks][0], a, acc[fr][0]);
          acc[fr][1] = MFMA(w1f[ks][1], a, acc[fr][1]);
        }
      }
      #pragma unroll
      for (int fr = 0; fr < 4; ++fr)
        #pragma unroll
        for (int fc = 0; fc < 2; ++fc) {
          int row = fr * 16 + l15;
          int kByte = (w * 32 + fc * 16 + lg * 4) * 2;
          u32x2 pk = pack4bf(fmaxf(acc[fr][fc][0] + b1v[fc].x, 0.f),
                             fmaxf(acc[fr][fc][1] + b1v[fc].y, 0.f),
                             fmaxf(acc[fr][fc][2] + b1v[fc].z, 0.f),
                             fmaxf(acc[fr][fc][3] + b1v[fc].w, 0.f));
          *(u32x2*)(h1 + ((row * 512 + kByte) ^ ((row & 7) << 4))) = pk;
        }
    }
    __syncthreads();                                   // B2
    {
      f32x4 acc[4];
      #pragma unroll
      for (int fr = 0; fr < 4; ++fr) acc[fr] = (f32x4){0.f, 0.f, 0.f, 0.f};
      #pragma unroll
      for (int ks = 0; ks < 8; ++ks) {
        int kb = ks * 64 + lg * 16;
        #pragma unroll
        for (int fr = 0; fr < 4; ++fr) {
          bf16x8 a = ldsFrag(h1, fr * 16 + l15, kb, 512);
          acc[fr] = MFMA(w2f[ks], a, acc[fr]);
        }
      }
      #pragma unroll
      for (int fr = 0; fr < 4; ++fr) {
        float p = fmaxf(acc[fr][0] + b2v.x, 0.f) * w3v.x
                + fmaxf(acc[fr][1] + b2v.y, 0.f) * w3v.y
                + fmaxf(acc[fr][2] + b2v.z, 0.f) * w3v.z
                + fmaxf(acc[fr][3] + b2v.w, 0.f) * w3v.w;
        p += __shfl_xor(p, 16);
        p += __shfl_xor(p, 32);
        if (lg == 0) red[par][fr * 16 + l15][w] = p;
      }
    }
    prevRow = rowBase;
    par ^= 1;
  }
  __syncthreads();
  if (prevRow >= 0 && t < 64) {
    float s = b3v;
    #pragma unroll
    for (int q = 0; q < 8; ++q) s += red[par ^ 1][t][q];
    out[prevRow + t] = s;
  }
}

extern "C" void kernel_launch(void* const* d_in, const int* in_sizes, int n_in,
                              void* d_out, int out_size, void* d_ws, size_t ws_size,
                              hipStream_t stream)
{
  const float* x1     = (const float*)d_in[0];
  const float* x2     = (const float*)d_in[1];
  const float* Ac     = (const float*)d_in[2];
  const int*   edge   = (const int*)d_in[3];
  const float* node_W = (const float*)d_in[4];
  const float* node_b = (const float*)d_in[5];
  const float* mlp_W  = (const float*)d_in[6];
  const float* mlp_b  = (const float*)d_in[7];
  const float* egL_W  = (const float*)d_in[8];
  const float* egL_b  = (const float*)d_in[9];
  const float* nro_W1 = (const float*)d_in[10];
  const float* nro_b1 = (const float*)d_in[11];
  const float* nro_W2 = (const float*)d_in[12];
  const float* nro_b2 = (const float*)d_in[13];
  const float* nro_W3 = (const float*)d_in[14];
  const float* nro_b3 = (const float*)d_in[15];
  const float* ero_W1 = (const float*)d_in[16];
  const float* ero_b1 = (const float*)d_in[17];
  const float* ero_W2 = (const float*)d_in[18];
  const float* ero_b2 = (const float*)d_in[19];
  const float* ero_W3 = (const float*)d_in[20];
  const float* ero_b3 = (const float*)d_in[21];
  float* out = (float*)d_out;

  const size_t xnElems = (size_t)NB * NT * 2 * ND;       // 8,388,608
  const size_t xeElems = (size_t)NB * NM * 4 * ND;       // 134,217,728
  const size_t wBytes  = 3 * 128 * 128 * 2 * 3
                       + 4 * (128 * 256 * 2);
  if (ws_size < xnElems * 3 * sizeof(float) + xeElems * 2 + wBytes) return;

  float* xn0 = (float*)d_ws;
  float* xn1 = xn0 + xnElems;
  float* xn2 = xn1 + xnElems;
  unsigned short* xeH = (unsigned short*)(xn2 + xnElems);
  char*  wWm = (char*)(xeH + xeElems);
  char*  wWe = wWm + 3 * 128 * 128 * 2;
  char*  wNd = wWe + 3 * 128 * 128 * 2;
  char*  wN1 = wNd + 3 * 128 * 128 * 2;
  char*  wN2 = wN1 + 128 * 256 * 2;
  char*  wE1 = wN2 + 128 * 256 * 2;
  char*  wE2 = wE1 + 128 * 256 * 2;

  int* deg    = (int*)d_out;
  int* off    = deg + NT;
  int* cursor = off + NT + 1;
  int* csr    = cursor + NT;

  // all weight prep in one launch (136 blocks)
  k_prep_all<<<136, 256, 0, stream>>>(mlp_W, egL_W, node_W,
                                      nro_W1, nro_W2, ero_W1, ero_W2,
                                      wWm, wWe, wNd, wN1, wN2, wE1, wE2);

  hipMemsetAsync(deg, 0, NT * sizeof(int), stream);
  k_csr_count<<<NM / 256, 256, 0, stream>>>(edge, deg);
  k_csr_scan<<<1, 64, 0, stream>>>(deg, off, cursor);
  k_csr_fill<<<NM / 256, 256, 0, stream>>>(edge, cursor, csr);
  k_csr_sort<<<NT / 256, 256, 0, stream>>>(off, csr);

  const int nTilesN = (NB * NT * 2) / 32;  // 2048
  k_node<<<1024, 256, 0, stream>>>(x1, xn0, Ac, edge, off, csr, wNd, node_b, 0, nTilesN);
  k_node<<<1024, 256, 0, stream>>>(xn0, xn1, Ac, edge, off, csr,
                                   wNd + 128 * 128 * 2, node_b + ND, 1, nTilesN);
  k_node<<<1024, 256, 0, stream>>>(xn1, xn2, Ac, edge, off, csr,
                                   wNd + 2 * 128 * 128 * 2, node_b + 2 * ND, 1, nTilesN);

  const int eTiles = (NB * NM * 4) / 64;   // 16384
  k_edge_mfma<1><<<512, 512, 0, stream>>>(xn0, x2, nullptr, xeH, edge,
                                          wWm, mlp_b, wWe, egL_b, 1, eTiles);
  k_edge_mfma<0><<<512, 512, 0, stream>>>(xn1, nullptr, xeH, xeH, edge,
                                          wWm + 128 * 128 * 2, mlp_b + ND,
                                          wWe + 128 * 128 * 2, egL_b + ND, 1, eTiles);
  k_edge_mfma<0><<<512, 512, 0, stream>>>(xn2, nullptr, xeH, xeH, edge,
                                          wWm + 2 * 128 * 128 * 2, mlp_b + 2 * ND,
                                          wWe + 2 * 128 * 128 * 2, egL_b + 2 * ND, 0, eTiles);
  k_ro_fused<1><<<512, 512, 0, stream>>>(nullptr, xeH, out + NB * NT * 2, eTiles,
                                         wE1, ero_b1, wE2, ero_b2, ero_W3, ero_b3);
  k_ro_fused<0><<<512, 512, 0, stream>>>(xn2, nullptr, out, (NB * NT * 2) / 64,
                                         wN1, nro_b1, wN2, nro_b2, nro_W3, nro_b3);
}